// Round 2
// baseline (483.776 us; speedup 1.0000x reference)
//
#include <hip/hip_runtime.h>
#include <hip/hip_bf16.h>
#include <cstdint>
#include <cstddef>

// Problem constants
#define N_NODES 50000
#define N_EDGES 1600000
#define N_REL 8
#define N_BASIS 4
#define DIM 240
#define NEG_SLOPE 0.01f

#define CAP_S1 4096     // max nodes needing layer-1 h (expected ~66)
#define CAP_B  65536    // max relevant edges (expected ~2100)
#define BITMAP_WORDS ((N_NODES + 31) / 32)

// ---- pass1: mark srcs of in-edges of {ci,si}; seed ci,si ----
__global__ __launch_bounds__(256) void k_pass1(const int* __restrict__ ei,
                                               const int* __restrict__ cip,
                                               const int* __restrict__ sip,
                                               unsigned* __restrict__ bitmap) {
    int e = blockIdx.x * 256 + threadIdx.x;
    int ci = cip[0], si = sip[0];
    if (blockIdx.x == 0 && threadIdx.x == 0) {
        atomicOr(&bitmap[ci >> 5], 1u << (ci & 31));
        atomicOr(&bitmap[si >> 5], 1u << (si & 31));
    }
    if (e < N_EDGES) {
        int dst = ei[N_EDGES + e];
        if (dst == ci || dst == si) {
            int src = ei[e];
            atomicOr(&bitmap[src >> 5], 1u << (src & 31));
        }
    }
}

// ---- compact: bitmap -> dense slots ----
__global__ __launch_bounds__(256) void k_compact(const unsigned* __restrict__ bitmap,
                                                 int* __restrict__ map,
                                                 int* __restrict__ nodes,
                                                 int* __restrict__ cnts) {
    int n = blockIdx.x * 256 + threadIdx.x;
    if (n < N_NODES && (bitmap[n >> 5] >> (n & 31)) & 1u) {
        int slot = atomicAdd(&cnts[0], 1);
        if (slot < CAP_S1) {
            map[n] = slot;
            nodes[slot] = n;
        }
    }
}

// ---- pass2: collect edges whose dst is marked ----
__global__ __launch_bounds__(256) void k_pass2(const int* __restrict__ ei,
                                               const int* __restrict__ et,
                                               const int* __restrict__ map,
                                               uint2* __restrict__ listB,
                                               int* __restrict__ cnts) {
    int e = blockIdx.x * 256 + threadIdx.x;
    if (e < N_EDGES) {
        int dst = ei[N_EDGES + e];
        int slot = map[dst];
        if (slot >= 0) {
            int pos = atomicAdd(&cnts[1], 1);
            if (pos < CAP_B) {
                unsigned src = (unsigned)ei[e];
                unsigned ty  = (unsigned)et[e];
                listB[pos] = make_uint2(src | (ty << 16), (unsigned)slot);
            }
        }
    }
}

// ---- layer-1 h for each slot ----
__global__ __launch_bounds__(256) void k_h1(const float* __restrict__ x,
                                            const uint2* __restrict__ listB,
                                            const int* __restrict__ nodes,
                                            const int* __restrict__ cnts,
                                            const float* __restrict__ compL,
                                            const float* __restrict__ basisL,
                                            const float* __restrict__ rootL,
                                            const float* __restrict__ biasL,
                                            float* __restrict__ h1c) {
    int slot = blockIdx.x;
    int nS1 = min(cnts[0], CAP_S1);
    if (slot >= nS1) return;
    int nB = min(cnts[1], CAP_B);
    int t = threadIdx.x;
    int node = nodes[slot];

    __shared__ float zs[N_BASIS][DIM];
    __shared__ float xb[DIM];

    float z0 = 0.f, z1 = 0.f, z2 = 0.f, z3 = 0.f;
    for (int i = 0; i < nB; i++) {
        uint2 ent = listB[i];
        if ((int)ent.y != slot) continue;
        int src = (int)(ent.x & 0xFFFFu);
        int ty  = (int)(ent.x >> 16);
        const float* c = compL + ty * N_BASIS;
        float c0 = c[0], c1 = c[1], c2 = c[2], c3 = c[3];
        if (t < DIM) {
            float xv = x[(size_t)src * DIM + t];
            z0 += c0 * xv; z1 += c1 * xv; z2 += c2 * xv; z3 += c3 * xv;
        }
    }
    if (t < DIM) {
        zs[0][t] = z0; zs[1][t] = z1; zs[2][t] = z2; zs[3][t] = z3;
        xb[t] = x[(size_t)node * DIM + t];
    }
    __syncthreads();
    if (t < DIM) {
        float acc = biasL[t];
        for (int i = 0; i < DIM; i++) {
            float xi = xb[i];
            acc += zs[0][i] * basisL[(size_t)(0 * DIM + i) * DIM + t];
            acc += zs[1][i] * basisL[(size_t)(1 * DIM + i) * DIM + t];
            acc += zs[2][i] * basisL[(size_t)(2 * DIM + i) * DIM + t];
            acc += zs[3][i] * basisL[(size_t)(3 * DIM + i) * DIM + t];
            acc += xi * rootL[(size_t)i * DIM + t];
        }
        acc = acc > 0.f ? acc : NEG_SLOPE * acc;  // layer 0: leaky relu
        h1c[(size_t)slot * DIM + t] = acc;
    }
}

// ---- layer-2 for {ci,si} + MLP head ----
__global__ __launch_bounds__(256) void k_h2head(const float* __restrict__ h1c,
                                                const uint2* __restrict__ listB,
                                                const int* __restrict__ map,
                                                const int* __restrict__ cnts,
                                                const float* __restrict__ compL,
                                                const float* __restrict__ basisL,
                                                const float* __restrict__ rootL,
                                                const float* __restrict__ biasL,
                                                const float* __restrict__ W1,
                                                const float* __restrict__ b1,
                                                const float* __restrict__ W2,
                                                const float* __restrict__ b2,
                                                const int* __restrict__ cip,
                                                const int* __restrict__ sip,
                                                float* __restrict__ out) {
    __shared__ float zs[N_BASIS][DIM];
    __shared__ float xb[DIM];
    __shared__ float h2s[2][DIM];   // [0]=concept, [1]=sentence
    __shared__ float cat[2 * DIM];
    __shared__ float red2[2];
    int t = threadIdx.x;
    int ci = cip[0], si = sip[0];
    int nB = min(cnts[1], CAP_B);

    for (int w = 0; w < 2; w++) {
        int node = w ? si : ci;
        int slot = map[node];
        float z0 = 0.f, z1 = 0.f, z2 = 0.f, z3 = 0.f;
        for (int i = 0; i < nB; i++) {
            uint2 ent = listB[i];
            if ((int)ent.y != slot) continue;
            int src = (int)(ent.x & 0xFFFFu);
            int ty  = (int)(ent.x >> 16);
            int ss = map[src];
            if (ss < 0) continue;
            const float* c = compL + ty * N_BASIS;
            float c0 = c[0], c1 = c[1], c2 = c[2], c3 = c[3];
            if (t < DIM) {
                float hv = h1c[(size_t)ss * DIM + t];
                z0 += c0 * hv; z1 += c1 * hv; z2 += c2 * hv; z3 += c3 * hv;
            }
        }
        if (t < DIM) {
            zs[0][t] = z0; zs[1][t] = z1; zs[2][t] = z2; zs[3][t] = z3;
            xb[t] = (slot >= 0) ? h1c[(size_t)slot * DIM + t] : 0.f;
        }
        __syncthreads();
        if (t < DIM) {
            float acc = biasL[t];
            for (int i = 0; i < DIM; i++) {
                float xi = xb[i];
                acc += zs[0][i] * basisL[(size_t)(0 * DIM + i) * DIM + t];
                acc += zs[1][i] * basisL[(size_t)(1 * DIM + i) * DIM + t];
                acc += zs[2][i] * basisL[(size_t)(2 * DIM + i) * DIM + t];
                acc += zs[3][i] * basisL[(size_t)(3 * DIM + i) * DIM + t];
                acc += xi * rootL[(size_t)i * DIM + t];
            }
            h2s[w][t] = acc;  // last layer: no relu
        }
        __syncthreads();
    }

    if (t < DIM) {
        float hc = h2s[0][t], hs = h2s[1][t];
        cat[t] = fabsf(hs - hc);
        cat[DIM + t] = hs * hc;
    }
    __syncthreads();
    if (t < 128) {
        float acc = b1[t];
        for (int k = 0; k < 2 * DIM; k++) acc += W1[(size_t)t * 2 * DIM + k] * cat[k];
        float hid = acc > 0.f ? acc : NEG_SLOPE * acc;
        float v = W2[t] * hid;
        for (int off = 32; off > 0; off >>= 1) v += __shfl_down(v, off);
        if ((t & 63) == 0) red2[t >> 6] = v;
    }
    __syncthreads();
    if (t == 0) out[0] = b2[0] + red2[0] + red2[1];
}

// ---------------- launch ----------------
extern "C" void kernel_launch(void* const* d_in, const int* in_sizes, int n_in,
                              void* d_out, int out_size, void* d_ws, size_t ws_size,
                              hipStream_t stream) {
    const float* x     = (const float*)d_in[0];
    const int*   ei    = (const int*)d_in[1];
    const int*   et    = (const int*)d_in[2];
    const float* comp  = (const float*)d_in[3];
    const float* basis = (const float*)d_in[4];
    const float* root  = (const float*)d_in[5];
    const float* bias  = (const float*)d_in[6];
    const float* W1    = (const float*)d_in[7];
    const float* b1    = (const float*)d_in[8];
    const float* W2    = (const float*)d_in[9];
    const float* b2    = (const float*)d_in[10];
    const int*   cip   = (const int*)d_in[11];
    const int*   sip   = (const int*)d_in[12];
    float* out = (float*)d_out;
    (void)n_in; (void)in_sizes; (void)out_size;

    char* ws = (char*)d_ws;
    size_t off = 0;
    auto alloc = [&](size_t bytes) -> char* {
        char* p = ws + off;
        off += (bytes + 255) & ~(size_t)255;
        return p;
    };
    int*      cnts   = (int*)alloc(2 * sizeof(int));
    unsigned* bitmap = (unsigned*)alloc(BITMAP_WORDS * sizeof(unsigned));
    int*      map    = (int*)alloc((size_t)N_NODES * sizeof(int));
    int*      nodes  = (int*)alloc((size_t)CAP_S1 * sizeof(int));
    uint2*    listB  = (uint2*)alloc((size_t)CAP_B * sizeof(uint2));
    float*    h1c    = (float*)alloc((size_t)CAP_S1 * DIM * sizeof(float));
    if (off > ws_size) return;  // ~4.7 MB total — should always fit

    hipMemsetAsync(cnts, 0, 2 * sizeof(int), stream);
    hipMemsetAsync(bitmap, 0, BITMAP_WORDS * sizeof(unsigned), stream);
    hipMemsetAsync(map, 0xFF, (size_t)N_NODES * sizeof(int), stream);  // -1

    int egrid = (N_EDGES + 255) / 256;  // 6250
    k_pass1<<<egrid, 256, 0, stream>>>(ei, cip, sip, bitmap);
    k_compact<<<(N_NODES + 255) / 256, 256, 0, stream>>>(bitmap, map, nodes, cnts);
    k_pass2<<<egrid, 256, 0, stream>>>(ei, et, map, listB, cnts);

    // layer 1 (l=0)
    k_h1<<<CAP_S1, 256, 0, stream>>>(x, listB, nodes, cnts,
                                     comp, basis, root, bias, h1c);
    // layer 2 (l=1) + head
    k_h2head<<<1, 256, 0, stream>>>(h1c, listB, map, cnts,
                                    comp + N_REL * N_BASIS,
                                    basis + (size_t)N_BASIS * DIM * DIM,
                                    root + (size_t)DIM * DIM,
                                    bias + DIM,
                                    W1, b1, W2, b2, cip, sip, out);
}

// Round 3
// 208.894 us; speedup vs baseline: 2.3159x; 2.3159x over previous
//
#include <hip/hip_runtime.h>
#include <cstdint>
#include <cstddef>

// Problem constants
#define N_NODES 50000
#define N_EDGES 1600000
#define N_REL 8
#define N_BASIS 4
#define DIM 240
#define NEG_SLOPE 0.01f

#define CAP_S1 1024    // max nodes needing layer-1 h (expected ~66)
#define CAP_DEG 512    // max in-degree of a relevant node (expected ~32)
#define BITMAP_WORDS ((N_NODES + 31) / 32)
#define NCH 8
#define CHUNK (DIM / NCH)  // 30

// ---- pass1: mark srcs of in-edges of {ci,si}; seed ci,si (int4-vectorized) ----
__global__ __launch_bounds__(256) void k_pass1(const int* __restrict__ ei,
                                               const int* __restrict__ cip,
                                               const int* __restrict__ sip,
                                               unsigned* __restrict__ bitmap) {
    int base = (blockIdx.x * 256 + threadIdx.x) * 4;
    int ci = cip[0], si = sip[0];
    if (blockIdx.x == 0 && threadIdx.x == 0) {
        atomicOr(&bitmap[ci >> 5], 1u << (ci & 31));
        atomicOr(&bitmap[si >> 5], 1u << (si & 31));
    }
    if (base < N_EDGES) {  // N_EDGES % 4 == 0 -> full int4 safe
        int4 d = *reinterpret_cast<const int4*>(ei + N_EDGES + base);
        int dv[4] = {d.x, d.y, d.z, d.w};
#pragma unroll
        for (int j = 0; j < 4; j++) {
            if (dv[j] == ci || dv[j] == si) {
                int src = ei[base + j];
                atomicOr(&bitmap[src >> 5], 1u << (src & 31));
            }
        }
    }
}

// ---- compact: bitmap -> dense slots ----
__global__ __launch_bounds__(256) void k_compact(const unsigned* __restrict__ bitmap,
                                                 int* __restrict__ map,
                                                 int* __restrict__ nodes,
                                                 int* __restrict__ cnts) {
    int n = blockIdx.x * 256 + threadIdx.x;
    if (n < N_NODES && ((bitmap[n >> 5] >> (n & 31)) & 1u)) {
        int slot = atomicAdd(&cnts[0], 1);
        if (slot < CAP_S1) {
            map[n] = slot;
            nodes[slot] = n;
        } else {
            map[n] = -1;
        }
    }
}

// ---- pass2: build slot-CSR of in-edges of marked nodes ----
__global__ __launch_bounds__(256) void k_pass2(const int* __restrict__ ei,
                                               const int* __restrict__ et,
                                               const unsigned* __restrict__ bitmap,
                                               const int* __restrict__ map,
                                               int* __restrict__ degs,
                                               unsigned* __restrict__ eslot) {
    int base = (blockIdx.x * 256 + threadIdx.x) * 4;
    if (base < N_EDGES) {
        int4 d = *reinterpret_cast<const int4*>(ei + N_EDGES + base);
        int dv[4] = {d.x, d.y, d.z, d.w};
#pragma unroll
        for (int j = 0; j < 4; j++) {
            int dst = dv[j];
            if ((bitmap[dst >> 5] >> (dst & 31)) & 1u) {
                int slot = map[dst];
                if (slot >= 0) {
                    int idx = atomicAdd(&degs[slot], 1);
                    if (idx < CAP_DEG) {
                        unsigned src = (unsigned)ei[base + j];
                        unsigned ty  = (unsigned)et[base + j];
                        eslot[(size_t)slot * CAP_DEG + idx] = src | (ty << 16);
                    }
                }
            }
        }
    }
}

// ---- layer-1 h for each slot (own edge list only) ----
__global__ __launch_bounds__(256) void k_h1(const float* __restrict__ x,
                                            const unsigned* __restrict__ eslot,
                                            const int* __restrict__ degs,
                                            const int* __restrict__ nodes,
                                            const int* __restrict__ cnts,
                                            const float* __restrict__ compL,
                                            const float* __restrict__ basisL,
                                            const float* __restrict__ rootL,
                                            const float* __restrict__ biasL,
                                            float* __restrict__ h1c) {
    int nS1 = min(cnts[0], CAP_S1);
    int t = threadIdx.x;
    __shared__ float zs[N_BASIS][DIM];
    __shared__ float xb[DIM];
    for (int slot = blockIdx.x; slot < nS1; slot += gridDim.x) {
        int node = nodes[slot];
        int deg = min(degs[slot], CAP_DEG);
        const unsigned* el = eslot + (size_t)slot * CAP_DEG;
        float z0 = 0.f, z1 = 0.f, z2 = 0.f, z3 = 0.f;
        for (int i = 0; i < deg; i++) {
            unsigned p = el[i];
            int src = (int)(p & 0xFFFFu);
            int ty  = (int)(p >> 16);
            const float* c = compL + ty * N_BASIS;
            float c0 = c[0], c1 = c[1], c2 = c[2], c3 = c[3];
            if (t < DIM) {
                float xv = x[(size_t)src * DIM + t];
                z0 += c0 * xv; z1 += c1 * xv; z2 += c2 * xv; z3 += c3 * xv;
            }
        }
        if (t < DIM) {
            zs[0][t] = z0; zs[1][t] = z1; zs[2][t] = z2; zs[3][t] = z3;
            xb[t] = x[(size_t)node * DIM + t];
        }
        __syncthreads();
        if (t < DIM) {
            float acc = biasL[t];
#pragma unroll 4
            for (int i = 0; i < DIM; i++) {
                acc += zs[0][i] * basisL[(size_t)(0 * DIM + i) * DIM + t];
                acc += zs[1][i] * basisL[(size_t)(1 * DIM + i) * DIM + t];
                acc += zs[2][i] * basisL[(size_t)(2 * DIM + i) * DIM + t];
                acc += zs[3][i] * basisL[(size_t)(3 * DIM + i) * DIM + t];
                acc += xb[i] * rootL[(size_t)i * DIM + t];
            }
            acc = acc > 0.f ? acc : NEG_SLOPE * acc;  // layer 0 activation
            h1c[(size_t)slot * DIM + t] = acc;
        }
        __syncthreads();
    }
}

// ---- layer-2 aggregation in basis space for {ci,si} ----
__global__ __launch_bounds__(256) void k_z2(const float* __restrict__ h1c,
                                            const unsigned* __restrict__ eslot,
                                            const int* __restrict__ degs,
                                            const int* __restrict__ map,
                                            const float* __restrict__ comp2,
                                            const int* __restrict__ cip,
                                            const int* __restrict__ sip,
                                            float* __restrict__ z2,
                                            float* __restrict__ xb2) {
    int w = blockIdx.x;  // 0=concept, 1=sentence
    int node = w ? sip[0] : cip[0];
    int slot = map[node];
    int t = threadIdx.x;
    int deg = (slot >= 0) ? min(degs[slot], CAP_DEG) : 0;
    const unsigned* el = eslot + (size_t)(slot >= 0 ? slot : 0) * CAP_DEG;
    float z0 = 0.f, z1 = 0.f, zr2 = 0.f, z3 = 0.f;
    for (int i = 0; i < deg; i++) {
        unsigned p = el[i];
        int src = (int)(p & 0xFFFFu);
        int ty  = (int)(p >> 16);
        int ss = map[src];
        const float* c = comp2 + ty * N_BASIS;
        float c0 = c[0], c1 = c[1], c2 = c[2], c3 = c[3];
        if (t < DIM && ss >= 0) {
            float hv = h1c[(size_t)ss * DIM + t];
            z0 += c0 * hv; z1 += c1 * hv; zr2 += c2 * hv; z3 += c3 * hv;
        }
    }
    if (t < DIM) {
        z2[(w * N_BASIS + 0) * DIM + t] = z0;
        z2[(w * N_BASIS + 1) * DIM + t] = z1;
        z2[(w * N_BASIS + 2) * DIM + t] = zr2;
        z2[(w * N_BASIS + 3) * DIM + t] = z3;
        xb2[w * DIM + t] = (slot >= 0) ? h1c[(size_t)slot * DIM + t] : 0.f;
    }
}

// ---- layer-2 GEMM: partial over i-chunks, atomicAdd merge ----
__global__ __launch_bounds__(256) void k_h2(const float* __restrict__ z2,
                                            const float* __restrict__ xb2,
                                            const float* __restrict__ basis2,
                                            const float* __restrict__ root2,
                                            float* __restrict__ h2acc) {
    int w = blockIdx.x, ch = blockIdx.y;
    int i0 = ch * CHUNK;
    int t = threadIdx.x;
    __shared__ float zc[N_BASIS][CHUNK];
    __shared__ float xc[CHUNK];
    if (t < CHUNK) {
        xc[t] = xb2[w * DIM + i0 + t];
#pragma unroll
        for (int b = 0; b < N_BASIS; b++)
            zc[b][t] = z2[(w * N_BASIS + b) * DIM + i0 + t];
    }
    __syncthreads();
    if (t < DIM) {
        float acc = 0.f;
#pragma unroll 5
        for (int ii = 0; ii < CHUNK; ii++) {
            int i = i0 + ii;
            acc += zc[0][ii] * basis2[(size_t)(0 * DIM + i) * DIM + t];
            acc += zc[1][ii] * basis2[(size_t)(1 * DIM + i) * DIM + t];
            acc += zc[2][ii] * basis2[(size_t)(2 * DIM + i) * DIM + t];
            acc += zc[3][ii] * basis2[(size_t)(3 * DIM + i) * DIM + t];
            acc += xc[ii] * root2[(size_t)i * DIM + t];
        }
        atomicAdd(&h2acc[w * DIM + t], acc);
    }
}

// ---- head MLP ----
__global__ __launch_bounds__(128) void k_head(const float* __restrict__ h2acc,
                                              const float* __restrict__ bias2,
                                              const float* __restrict__ W1,
                                              const float* __restrict__ b1,
                                              const float* __restrict__ W2,
                                              const float* __restrict__ b2,
                                              float* __restrict__ out) {
    __shared__ float cat[2 * DIM];
    __shared__ float red2[2];
    int t = threadIdx.x;
    for (int k = t; k < DIM; k += 128) {
        float hc = h2acc[k] + bias2[k];          // concept (no relu on last layer)
        float hs = h2acc[DIM + k] + bias2[k];    // sentence
        cat[k] = fabsf(hs - hc);
        cat[DIM + k] = hs * hc;
    }
    __syncthreads();
    float acc = b1[t];
    const float4* wrow = reinterpret_cast<const float4*>(W1 + (size_t)t * 2 * DIM);
#pragma unroll 8
    for (int k = 0; k < (2 * DIM) / 4; k++) {
        float4 wv = wrow[k];
        acc += wv.x * cat[k * 4] + wv.y * cat[k * 4 + 1] +
               wv.z * cat[k * 4 + 2] + wv.w * cat[k * 4 + 3];
    }
    float hid = acc > 0.f ? acc : NEG_SLOPE * acc;
    float v = W2[t] * hid;
    for (int off = 32; off > 0; off >>= 1) v += __shfl_down(v, off);
    if ((t & 63) == 0) red2[t >> 6] = v;
    __syncthreads();
    if (t == 0) out[0] = b2[0] + red2[0] + red2[1];
}

// ---------------- launch ----------------
extern "C" void kernel_launch(void* const* d_in, const int* in_sizes, int n_in,
                              void* d_out, int out_size, void* d_ws, size_t ws_size,
                              hipStream_t stream) {
    const float* x     = (const float*)d_in[0];
    const int*   ei    = (const int*)d_in[1];
    const int*   et    = (const int*)d_in[2];
    const float* comp  = (const float*)d_in[3];
    const float* basis = (const float*)d_in[4];
    const float* root  = (const float*)d_in[5];
    const float* bias  = (const float*)d_in[6];
    const float* W1    = (const float*)d_in[7];
    const float* b1    = (const float*)d_in[8];
    const float* W2    = (const float*)d_in[9];
    const float* b2    = (const float*)d_in[10];
    const int*   cip   = (const int*)d_in[11];
    const int*   sip   = (const int*)d_in[12];
    float* out = (float*)d_out;
    (void)n_in; (void)in_sizes; (void)out_size;

    char* ws = (char*)d_ws;
    size_t off = 0;
    auto alloc = [&](size_t bytes) -> char* {
        char* p = ws + off;
        off += (bytes + 255) & ~(size_t)255;
        return p;
    };
    int*      cnts   = (int*)alloc(2 * sizeof(int));
    unsigned* bitmap = (unsigned*)alloc(BITMAP_WORDS * sizeof(unsigned));
    int*      map    = (int*)alloc((size_t)N_NODES * sizeof(int));     // NOT memset (bitmap-guarded)
    int*      nodes  = (int*)alloc((size_t)CAP_S1 * sizeof(int));
    int*      degs   = (int*)alloc((size_t)CAP_S1 * sizeof(int));
    unsigned* eslot  = (unsigned*)alloc((size_t)CAP_S1 * CAP_DEG * sizeof(unsigned));  // 2 MB
    float*    h1c    = (float*)alloc((size_t)CAP_S1 * DIM * sizeof(float));            // ~1 MB
    float*    z2     = (float*)alloc((size_t)2 * N_BASIS * DIM * sizeof(float));
    float*    xb2    = (float*)alloc((size_t)2 * DIM * sizeof(float));
    float*    h2acc  = (float*)alloc((size_t)2 * DIM * sizeof(float));
    if (off > ws_size) return;

    hipMemsetAsync(cnts, 0, 2 * sizeof(int), stream);
    hipMemsetAsync(bitmap, 0, BITMAP_WORDS * sizeof(unsigned), stream);
    hipMemsetAsync(degs, 0, (size_t)CAP_S1 * sizeof(int), stream);
    hipMemsetAsync(h2acc, 0, (size_t)2 * DIM * sizeof(float), stream);

    const float* comp2  = comp  + N_REL * N_BASIS;
    const float* basis2 = basis + (size_t)N_BASIS * DIM * DIM;
    const float* root2  = root  + (size_t)DIM * DIM;
    const float* bias2  = bias  + DIM;

    int egrid4 = (N_EDGES / 4 + 255) / 256;  // 1563
    k_pass1<<<egrid4, 256, 0, stream>>>(ei, cip, sip, bitmap);
    k_compact<<<(N_NODES + 255) / 256, 256, 0, stream>>>(bitmap, map, nodes, cnts);
    k_pass2<<<egrid4, 256, 0, stream>>>(ei, et, bitmap, map, degs, eslot);

    k_h1<<<128, 256, 0, stream>>>(x, eslot, degs, nodes, cnts,
                                  comp, basis, root, bias, h1c);
    k_z2<<<2, 256, 0, stream>>>(h1c, eslot, degs, map, comp2, cip, sip, z2, xb2);
    k_h2<<<dim3(2, NCH), 256, 0, stream>>>(z2, xb2, basis2, root2, h2acc);
    k_head<<<1, 128, 0, stream>>>(h2acc, bias2, W1, b1, W2, b2, out);
}

// Round 4
// 170.928 us; speedup vs baseline: 2.8303x; 1.2221x over previous
//
#include <hip/hip_runtime.h>
#include <cstdint>
#include <cstddef>

// Problem constants
#define N_NODES 50000
#define N_EDGES 1600000
#define N_REL 8
#define N_BASIS 4
#define DIM 240
#define NEG_SLOPE 0.01f

#define CAP_S1 256     // max nodes needing layer-1 h (expected ~66; Poisson(32)x2 + seeds)
#define CAP_DEG 128    // max in-degree of a relevant node (Poisson(32); P(>128) ~ 0)
#define BITMAP_WORDS ((N_NODES + 31) / 32)
#define NCH 8
#define CHUNK (DIM / NCH)  // 30

__device__ __forceinline__ float lrelu(float v) { return v > 0.f ? v : NEG_SLOPE * v; }

// ---- pass1: mark srcs of in-edges of {ci,si}; seed ci,si (int4-vectorized) ----
__global__ __launch_bounds__(256) void k_pass1(const int* __restrict__ ei,
                                               const int* __restrict__ cip,
                                               const int* __restrict__ sip,
                                               unsigned* __restrict__ bitmap) {
    int base = (blockIdx.x * 256 + threadIdx.x) * 4;
    int ci = cip[0], si = sip[0];
    if (blockIdx.x == 0 && threadIdx.x == 0) {
        atomicOr(&bitmap[ci >> 5], 1u << (ci & 31));
        atomicOr(&bitmap[si >> 5], 1u << (si & 31));
    }
    if (base < N_EDGES) {  // N_EDGES % 4 == 0
        int4 d = *reinterpret_cast<const int4*>(ei + N_EDGES + base);
        int dv[4] = {d.x, d.y, d.z, d.w};
#pragma unroll
        for (int j = 0; j < 4; j++) {
            if (dv[j] == ci || dv[j] == si) {
                int src = ei[base + j];
                atomicOr(&bitmap[src >> 5], 1u << (src & 31));
            }
        }
    }
}

// ---- compact: bitmap -> dense slots ----
__global__ __launch_bounds__(256) void k_compact(const unsigned* __restrict__ bitmap,
                                                 int* __restrict__ map,
                                                 int* __restrict__ nodes,
                                                 int* __restrict__ cnts) {
    int n = blockIdx.x * 256 + threadIdx.x;
    if (n < N_NODES && ((bitmap[n >> 5] >> (n & 31)) & 1u)) {
        int slot = atomicAdd(&cnts[0], 1);
        if (slot < CAP_S1) {
            map[n] = slot;
            nodes[slot] = n;
        } else {
            map[n] = -1;
        }
    }
}

// ---- pass2: build slot-CSR of in-edges of marked nodes ----
__global__ __launch_bounds__(256) void k_pass2(const int* __restrict__ ei,
                                               const int* __restrict__ et,
                                               const unsigned* __restrict__ bitmap,
                                               const int* __restrict__ map,
                                               int* __restrict__ degs,
                                               unsigned* __restrict__ eslot) {
    int base = (blockIdx.x * 256 + threadIdx.x) * 4;
    if (base < N_EDGES) {
        int4 d = *reinterpret_cast<const int4*>(ei + N_EDGES + base);
        int dv[4] = {d.x, d.y, d.z, d.w};
#pragma unroll
        for (int j = 0; j < 4; j++) {
            int dst = dv[j];
            if ((bitmap[dst >> 5] >> (dst & 31)) & 1u) {
                int slot = map[dst];
                if (slot >= 0) {
                    int idx = atomicAdd(&degs[slot], 1);
                    if (idx < CAP_DEG) {
                        unsigned src = (unsigned)ei[base + j];
                        unsigned ty  = (unsigned)et[base + j];
                        eslot[(size_t)slot * CAP_DEG + idx] = src | (ty << 16);
                    }
                }
            }
        }
    }
}

// ---- layer-1 aggregation: z1[slot][0..3] = sum_e comp[et_e]*x[src_e]; z1[slot][4]=x[node] ----
__global__ __launch_bounds__(256) void k_z1(const float* __restrict__ x,
                                            const unsigned* __restrict__ eslot,
                                            const int* __restrict__ degs,
                                            const int* __restrict__ nodes,
                                            const int* __restrict__ cnts,
                                            const float* __restrict__ compL,
                                            float* __restrict__ z1) {
    int slot = blockIdx.x;
    if (slot >= min(cnts[0], CAP_S1)) return;
    int t = threadIdx.x;
    __shared__ unsigned els[CAP_DEG];
    __shared__ float cs[N_REL * N_BASIS];
    int deg = min(degs[slot], CAP_DEG);
    if (t < N_REL * N_BASIS) cs[t] = compL[t];
    if (t < deg) els[t] = eslot[(size_t)slot * CAP_DEG + t];
    __syncthreads();
    if (t < DIM) {
        float z0 = 0.f, z1a = 0.f, z2a = 0.f, z3a = 0.f;
        int base = 0;
        for (; base + 4 <= deg; base += 4) {
            float xv[4];
            int ty[4];
#pragma unroll
            for (int j = 0; j < 4; j++) {
                unsigned p = els[base + j];
                int src = (int)(p & 0xFFFFu);
                ty[j] = (int)(p >> 16);
                xv[j] = x[(size_t)src * DIM + t];   // 4 independent loads in flight
            }
#pragma unroll
            for (int j = 0; j < 4; j++) {
                const float* c = &cs[ty[j] * N_BASIS];
                z0 += c[0] * xv[j]; z1a += c[1] * xv[j];
                z2a += c[2] * xv[j]; z3a += c[3] * xv[j];
            }
        }
        for (; base < deg; base++) {
            unsigned p = els[base];
            int src = (int)(p & 0xFFFFu);
            const float* c = &cs[(p >> 16) * N_BASIS];
            float xv = x[(size_t)src * DIM + t];
            z0 += c[0] * xv; z1a += c[1] * xv; z2a += c[2] * xv; z3a += c[3] * xv;
        }
        int node = nodes[slot];
        float xn = x[(size_t)node * DIM + t];
        float* zp = z1 + (size_t)slot * 5 * DIM;
        zp[0 * DIM + t] = z0;  zp[1 * DIM + t] = z1a;
        zp[2 * DIM + t] = z2a; zp[3 * DIM + t] = z3a;
        zp[4 * DIM + t] = xn;
    }
}

// ---- layer-1 GEMM, i-chunked partials: h1raw[slot][j] += sum_{i in chunk} z1[slot][*][i]*W ----
__global__ __launch_bounds__(256) void k_hgemm(const float* __restrict__ z1,
                                               const int* __restrict__ cnts,
                                               const float* __restrict__ basisL,
                                               const float* __restrict__ rootL,
                                               float* __restrict__ h1raw) {
    int slot = blockIdx.x;
    if (slot >= min(cnts[0], CAP_S1)) return;
    int ch = blockIdx.y;
    int i0 = ch * CHUNK;
    int t = threadIdx.x;
    __shared__ float zc[5][CHUNK];
    if (t < 5 * CHUNK) {
        int b = t / CHUNK, ii = t % CHUNK;
        zc[b][ii] = z1[((size_t)slot * 5 + b) * DIM + i0 + ii];
    }
    __syncthreads();
    if (t < DIM) {
        float acc = 0.f;
#pragma unroll 5
        for (int ii = 0; ii < CHUNK; ii++) {
            int i = i0 + ii;
            acc += zc[0][ii] * basisL[(size_t)(0 * DIM + i) * DIM + t];
            acc += zc[1][ii] * basisL[(size_t)(1 * DIM + i) * DIM + t];
            acc += zc[2][ii] * basisL[(size_t)(2 * DIM + i) * DIM + t];
            acc += zc[3][ii] * basisL[(size_t)(3 * DIM + i) * DIM + t];
            acc += zc[4][ii] * rootL[(size_t)i * DIM + t];
        }
        atomicAdd(&h1raw[(size_t)slot * DIM + t], acc);
    }
}

// ---- layer-2 fused: per (w, chunk) aggregate z (8 edges/round) then chunk-GEMM ----
__global__ __launch_bounds__(256) void k_zh2(const float* __restrict__ h1raw,
                                             const unsigned* __restrict__ eslot,
                                             const int* __restrict__ degs,
                                             const int* __restrict__ map,
                                             const float* __restrict__ comp2,
                                             const float* __restrict__ bias1,
                                             const float* __restrict__ basis2,
                                             const float* __restrict__ root2,
                                             const int* __restrict__ cip,
                                             const int* __restrict__ sip,
                                             float* __restrict__ h2acc) {
    int w = blockIdx.x, ch = blockIdx.y;
    int i0 = ch * CHUNK;
    int t = threadIdx.x;
    __shared__ unsigned els[CAP_DEG];
    __shared__ float cs[N_REL * N_BASIS];
    __shared__ float zpart[8][N_BASIS][CHUNK];
    __shared__ float zc[5][CHUNK];
    int node = w ? sip[0] : cip[0];
    int slot = map[node];  // always marked (seeded)
    int deg = (slot >= 0) ? min(degs[slot], CAP_DEG) : 0;
    if (t < N_REL * N_BASIS) cs[t] = comp2[t];
    if (t < deg) els[t] = eslot[(size_t)slot * CAP_DEG + t];
    __syncthreads();
    if (t < 8 * CHUNK) {
        int e8 = t / CHUNK, d = t % CHUNK;
        float za0 = 0.f, za1 = 0.f, za2 = 0.f, za3 = 0.f;
        for (int base = 0; base < deg; base += 8) {
            int e = base + e8;
            if (e < deg) {
                unsigned p = els[e];
                int src = (int)(p & 0xFFFFu);
                int ty  = (int)(p >> 16);
                int ss = map[src];
                float hv = 0.f;
                if (ss >= 0)
                    hv = lrelu(h1raw[(size_t)ss * DIM + i0 + d] + bias1[i0 + d]);
                const float* c = &cs[ty * N_BASIS];
                za0 += c[0] * hv; za1 += c[1] * hv; za2 += c[2] * hv; za3 += c[3] * hv;
            }
        }
        zpart[e8][0][d] = za0; zpart[e8][1][d] = za1;
        zpart[e8][2][d] = za2; zpart[e8][3][d] = za3;
    }
    __syncthreads();
    if (t < N_BASIS * CHUNK) {
        int b = t / CHUNK, d = t % CHUNK;
        float s = 0.f;
#pragma unroll
        for (int e = 0; e < 8; e++) s += zpart[e][b][d];
        zc[b][d] = s;
    } else if (t >= N_BASIS * CHUNK && t < 5 * CHUNK) {
        int d = t - N_BASIS * CHUNK;
        float r = (slot >= 0) ? lrelu(h1raw[(size_t)slot * DIM + i0 + d] + bias1[i0 + d]) : 0.f;
        zc[4][d] = r;
    }
    __syncthreads();
    if (t < DIM) {
        float acc = 0.f;
#pragma unroll 5
        for (int ii = 0; ii < CHUNK; ii++) {
            int i = i0 + ii;
            acc += zc[0][ii] * basis2[(size_t)(0 * DIM + i) * DIM + t];
            acc += zc[1][ii] * basis2[(size_t)(1 * DIM + i) * DIM + t];
            acc += zc[2][ii] * basis2[(size_t)(2 * DIM + i) * DIM + t];
            acc += zc[3][ii] * basis2[(size_t)(3 * DIM + i) * DIM + t];
            acc += zc[4][ii] * root2[(size_t)i * DIM + t];
        }
        atomicAdd(&h2acc[w * DIM + t], acc);
    }
}

// ---- head MLP: 512 threads, 4-way row split ----
__global__ __launch_bounds__(512) void k_head(const float* __restrict__ h2acc,
                                              const float* __restrict__ bias2,
                                              const float* __restrict__ W1,
                                              const float* __restrict__ b1,
                                              const float* __restrict__ W2,
                                              const float* __restrict__ b2,
                                              float* __restrict__ out) {
    __shared__ float cat[2 * DIM];
    __shared__ float part[128][4];
    __shared__ float hid[128];
    int t = threadIdx.x;
    if (t < DIM) {
        float hc = h2acc[t] + bias2[t];
        float hs = h2acc[DIM + t] + bias2[t];
        cat[t] = fabsf(hs - hc);
        cat[DIM + t] = hs * hc;
    }
    __syncthreads();
    int r = t >> 2, q = t & 3;
    const float4* wr = reinterpret_cast<const float4*>(W1 + (size_t)r * 2 * DIM) + q * 30;
    const float4* cq = reinterpret_cast<const float4*>(cat) + q * 30;
    float acc = 0.f;
#pragma unroll 6
    for (int k = 0; k < 30; k++) {
        float4 wv = wr[k];
        float4 cv = cq[k];
        acc += wv.x * cv.x + wv.y * cv.y + wv.z * cv.z + wv.w * cv.w;
    }
    part[r][q] = acc;
    __syncthreads();
    if (q == 0) {
        float s = part[r][0] + part[r][1] + part[r][2] + part[r][3] + b1[r];
        hid[r] = lrelu(s) * W2[r];
    }
    __syncthreads();
    if (t < 64) {
        float v = hid[t] + hid[t + 64];
        for (int off = 32; off > 0; off >>= 1) v += __shfl_down(v, off);
        if (t == 0) out[0] = b2[0] + v;
    }
}

// ---------------- launch ----------------
extern "C" void kernel_launch(void* const* d_in, const int* in_sizes, int n_in,
                              void* d_out, int out_size, void* d_ws, size_t ws_size,
                              hipStream_t stream) {
    const float* x     = (const float*)d_in[0];
    const int*   ei    = (const int*)d_in[1];
    const int*   et    = (const int*)d_in[2];
    const float* comp  = (const float*)d_in[3];
    const float* basis = (const float*)d_in[4];
    const float* root  = (const float*)d_in[5];
    const float* bias  = (const float*)d_in[6];
    const float* W1    = (const float*)d_in[7];
    const float* b1    = (const float*)d_in[8];
    const float* W2    = (const float*)d_in[9];
    const float* b2    = (const float*)d_in[10];
    const int*   cip   = (const int*)d_in[11];
    const int*   sip   = (const int*)d_in[12];
    float* out = (float*)d_out;
    (void)n_in; (void)in_sizes; (void)out_size;

    char* ws = (char*)d_ws;
    size_t off = 0;
    auto alloc = [&](size_t bytes) -> char* {
        char* p = ws + off;
        off += (bytes + 255) & ~(size_t)255;
        return p;
    };
    // ---- contiguous zero-region ----
    size_t zbeg = off;
    int*      cnts   = (int*)alloc(2 * sizeof(int));
    int*      degs   = (int*)alloc((size_t)CAP_S1 * sizeof(int));
    unsigned* bitmap = (unsigned*)alloc(BITMAP_WORDS * sizeof(unsigned));
    float*    h2acc  = (float*)alloc((size_t)2 * DIM * sizeof(float));
    float*    h1raw  = (float*)alloc((size_t)CAP_S1 * DIM * sizeof(float));  // 245 KB
    size_t zend = off;
    // ---- not zeroed ----
    int*      map    = (int*)alloc((size_t)N_NODES * sizeof(int));   // bitmap-guarded
    int*      nodes  = (int*)alloc((size_t)CAP_S1 * sizeof(int));
    unsigned* eslot  = (unsigned*)alloc((size_t)CAP_S1 * CAP_DEG * sizeof(unsigned));
    float*    z1     = (float*)alloc((size_t)CAP_S1 * 5 * DIM * sizeof(float));
    if (off > ws_size) return;

    hipMemsetAsync(ws + zbeg, 0, zend - zbeg, stream);

    const float* comp2  = comp  + N_REL * N_BASIS;
    const float* basis2 = basis + (size_t)N_BASIS * DIM * DIM;
    const float* root2  = root  + (size_t)DIM * DIM;
    const float* bias2  = bias  + DIM;

    int egrid4 = (N_EDGES / 4 + 255) / 256;  // 1563
    k_pass1<<<egrid4, 256, 0, stream>>>(ei, cip, sip, bitmap);
    k_compact<<<(N_NODES + 255) / 256, 256, 0, stream>>>(bitmap, map, nodes, cnts);
    k_pass2<<<egrid4, 256, 0, stream>>>(ei, et, bitmap, map, degs, eslot);

    k_z1<<<CAP_S1, 256, 0, stream>>>(x, eslot, degs, nodes, cnts, comp, z1);
    k_hgemm<<<dim3(CAP_S1, NCH), 256, 0, stream>>>(z1, cnts, basis, root, h1raw);
    k_zh2<<<dim3(2, NCH), 256, 0, stream>>>(h1raw, eslot, degs, map, comp2, bias,
                                            basis2, root2, cip, sip, h2acc);
    k_head<<<1, 512, 0, stream>>>(h2acc, bias2, W1, b1, W2, b2, out);
}